// Round 1
// baseline (146.803 us; speedup 1.0000x reference)
//
#include <hip/hip_runtime.h>
#include <math.h>

#define NF 1024
#define DIM 256
#define BATCH 2048
#define ROWS 16          // batch rows per k_main block
#define FCHUNK 512       // formulas per k_main block
#define NCHUNK (NF / FCHUNK)   // 2
#define NFT (FCHUNK / 256)     // formulas per thread = 2

// ws layout:
//   [0, 2MB)            : wT  float2[DIM][NF]  = (s2, -2*s2*mu)
//   [2MB, 2MB+4KB)      : c   float[NF]        = sum_d s2*mu^2
//   [2MB+4KB, +16KB)    : rowPartial float[NCHUNK][BATCH]
#define WS_WT_BYTES   (DIM * NF * 8)
#define WS_C_OFF      WS_WT_BYTES
#define WS_RP_OFF     (WS_WT_BYTES + NF * 4)

// ---------------------------------------------------------------------------
// K1: per-formula transform. block = formula f (coalesced mu/sigma reads),
// thread = dim d. Writes wT transposed (scattered 8B writes -- 2MB total,
// absorbed by L2; negligible vs main kernel). Also block-reduces c[f].
__global__ __launch_bounds__(DIM) void k_prep(const float* __restrict__ mu,
                                              const float* __restrict__ sigma,
                                              float2* __restrict__ wT,
                                              float* __restrict__ c) {
    const int f = blockIdx.x;
    const int d = threadIdx.x;
    const float m = mu[f * DIM + d];
    const float s = sigma[f * DIM + d];
    const float s2 = s * s;
    wT[d * NF + f] = make_float2(s2, -2.0f * s2 * m);

    float cp = s2 * m * m;
    #pragma unroll
    for (int off = 32; off > 0; off >>= 1) cp += __shfl_down(cp, off, 64);
    __shared__ float red[4];
    const int lane = threadIdx.x & 63, wv = threadIdx.x >> 6;
    if (lane == 0) red[wv] = cp;
    __syncthreads();
    if (threadIdx.x == 0) c[f] = red[0] + red[1] + red[2] + red[3];
}

// ---------------------------------------------------------------------------
// K2: fused dist^2 GEMM + exp + softmax-numerator. Grid (BATCH/ROWS, NCHUNK).
// Each block: ROWS batch rows x FCHUNK formulas. x rows staged in LDS as
// (x, x^2) float2; inner loop over d broadcasts LDS pairs, coalesced float2
// weight loads. Writes p = exp(g*exp(-dist)) to out and deterministic
// per-(chunk,row) partial sums (no atomics).
__global__ __launch_bounds__(256) void k_main(const float* __restrict__ x,
                                              const float2* __restrict__ wT,
                                              const float* __restrict__ c,
                                              const float* __restrict__ temp,
                                              float* __restrict__ out,
                                              float* __restrict__ rowPartial) {
    const int rowBlk = blockIdx.x;
    const int fc = blockIdx.y;
    const int t = threadIdx.x;
    const int r0 = rowBlk * ROWS;

    __shared__ float2 xs[ROWS][DIM];            // 32 KB
    __shared__ float red[4][ROWS];

    #pragma unroll
    for (int i = t; i < ROWS * DIM; i += 256) {
        const int r = i >> 8;                   // /DIM
        const int d = i & (DIM - 1);
        const float v = x[(r0 + r) * DIM + d];
        xs[r][d] = make_float2(v, v * v);
    }
    __syncthreads();

    const int fbase = fc * FCHUNK + t;
    float acc[ROWS][NFT];
    #pragma unroll
    for (int r = 0; r < ROWS; ++r)
        #pragma unroll
        for (int j = 0; j < NFT; ++j) acc[r][j] = 0.0f;

    #pragma unroll 2
    for (int d = 0; d < DIM; ++d) {
        const float2 w0 = wT[d * NF + fbase];
        const float2 w1 = wT[d * NF + fbase + 256];
        #pragma unroll
        for (int r = 0; r < ROWS; ++r) {
            const float2 xv = xs[r][d];
            acc[r][0] = fmaf(w0.x, xv.y, fmaf(w0.y, xv.x, acc[r][0]));
            acc[r][1] = fmaf(w1.x, xv.y, fmaf(w1.y, xv.x, acc[r][1]));
        }
    }

    const float g = 1.0f / (1.0f + __expf(-temp[0]));   // sigmoid(T)
    float psum[ROWS];
    #pragma unroll
    for (int r = 0; r < ROWS; ++r) psum[r] = 0.0f;

    #pragma unroll
    for (int j = 0; j < NFT; ++j) {
        const float cf = c[fbase + j * 256];
        #pragma unroll
        for (int r = 0; r < ROWS; ++r) {
            const float dist2 = acc[r][j] + cf;
            const float dist = sqrtf(fmaxf(dist2, 0.0f));
            const float loc = __expf(-dist);
            const float p = __expf(g * loc);    // softmax numerator (logits in (0,0.88], no max-sub needed)
            out[(r0 + r) * NF + fbase + j * 256] = p;
            psum[r] += p;
        }
    }

    // block-reduce psum[r] over 256 threads -> rowPartial[fc][r0+r]
    const int lane = t & 63, wv = t >> 6;
    #pragma unroll
    for (int r = 0; r < ROWS; ++r) {
        float v = psum[r];
        #pragma unroll
        for (int off = 32; off > 0; off >>= 1) v += __shfl_down(v, off, 64);
        if (lane == 0) red[wv][r] = v;
    }
    __syncthreads();
    if (t < ROWS) {
        rowPartial[fc * BATCH + r0 + t] =
            red[0][t] + red[1][t] + red[2][t] + red[3][t];
    }
}

// ---------------------------------------------------------------------------
// K3: in-place normalize: out[row][f] /= sum_chunks rowPartial[chunk][row]
__global__ __launch_bounds__(256) void k_norm(float* __restrict__ out,
                                              const float* __restrict__ rowPartial) {
    const int i = blockIdx.x * 256 + threadIdx.x;     // float4 index
    const int row = i >> 8;                           // / (NF/4)
    float s = 0.0f;
    #pragma unroll
    for (int ch = 0; ch < NCHUNK; ++ch) s += rowPartial[ch * BATCH + row];
    const float inv = 1.0f / s;
    float4* o4 = (float4*)out;
    float4 v = o4[i];
    v.x *= inv; v.y *= inv; v.z *= inv; v.w *= inv;
    o4[i] = v;
}

extern "C" void kernel_launch(void* const* d_in, const int* in_sizes, int n_in,
                              void* d_out, int out_size, void* d_ws, size_t ws_size,
                              hipStream_t stream) {
    const float* x     = (const float*)d_in[0];
    const float* mu    = (const float*)d_in[1];
    const float* sigma = (const float*)d_in[2];
    const float* temp  = (const float*)d_in[3];
    float* out = (float*)d_out;

    char* ws = (char*)d_ws;
    float2* wT        = (float2*)ws;
    float*  c         = (float*)(ws + WS_C_OFF);
    float*  rowPartial = (float*)(ws + WS_RP_OFF);

    k_prep<<<NF, DIM, 0, stream>>>(mu, sigma, wT, c);

    dim3 g2(BATCH / ROWS, NCHUNK);
    k_main<<<g2, 256, 0, stream>>>(x, wT, c, temp, out, rowPartial);

    k_norm<<<(BATCH * NF / 4) / 256, 256, 0, stream>>>(out, rowPartial);
}

// Round 2
// 83.388 us; speedup vs baseline: 1.7605x; 1.7605x over previous
//
#include <hip/hip_runtime.h>
#include <math.h>

#define NF 1024
#define DIM 256
#define BATCH 2048
#define K 512            // interleaved (x^2, x) pairs -> 2*DIM
#define BM 64            // batch rows per k_main block
#define BN 64            // formulas per k_main block
#define KB 64            // K elements staged per iteration (= 32 dims)
#define LDA 80           // A_lds row stride in bf16 elems (64 + 16 pad, keeps 16B align)
#define NCHUNK (NF / BN) // 16 col-chunks -> rowPartial slices

// ws layout (16B aligned):
//   [0, 1MB)        : Bb   bf16[NF][K]   rows: (s2, -2*s2*mu) interleaved per dim
//   [1MB, +4KB)     : c    float[NF]     = sum_d s2*mu^2
//   [1MB+4KB, ...)  : rowPartial float[NCHUNK][BATCH]   (128 KB)
#define WS_B_BYTES  (NF * K * 2)
#define WS_C_OFF    WS_B_BYTES
#define WS_RP_OFF   (WS_B_BYTES + NF * 4)

typedef __attribute__((ext_vector_type(8))) short short8;   // 8 bf16 (4 VGPRs)
typedef __attribute__((ext_vector_type(4))) float f32x4;    // MFMA accumulator

__device__ inline unsigned short f2bf(float f) {
    unsigned u = __float_as_uint(f);
    u += 0x7fffu + ((u >> 16) & 1u);       // round-to-nearest-even
    return (unsigned short)(u >> 16);
}

// ---------------------------------------------------------------------------
// K1: blocks 0..1023: formula f -> Bb row (coalesced 4B stores) + c[f].
//     blocks 1024..1055: zero rowPartial (float4 stores).
__global__ __launch_bounds__(256) void k_prep(const float* __restrict__ mu,
                                              const float* __restrict__ sigma,
                                              unsigned int* __restrict__ Bb32,
                                              float* __restrict__ c,
                                              float4* __restrict__ rowPartial4) {
    const int t = threadIdx.x;
    if (blockIdx.x >= NF) {
        const int zb = blockIdx.x - NF;
        rowPartial4[zb * 256 + t] = make_float4(0.f, 0.f, 0.f, 0.f);
        return;
    }
    const int f = blockIdx.x;
    const float m = mu[f * DIM + t];
    const float s = sigma[f * DIM + t];
    const float s2 = s * s;
    const float w = -2.0f * s2 * m;
    // k=2d -> s2, k=2d+1 -> w (little-endian pack)
    Bb32[f * DIM + t] = (unsigned)f2bf(s2) | ((unsigned)f2bf(w) << 16);

    float cp = s2 * m * m;
    #pragma unroll
    for (int off = 32; off > 0; off >>= 1) cp += __shfl_down(cp, off, 64);
    __shared__ float red[4];
    const int lane = t & 63, wv = t >> 6;
    if (lane == 0) red[wv] = cp;
    __syncthreads();
    if (t == 0) c[f] = red[0] + red[1] + red[2] + red[3];
}

// ---------------------------------------------------------------------------
// K2: bf16 MFMA GEMM (dist^2) + exp epilogue + deterministic row partials.
// Grid (BATCH/BM, NF/BN) = (32,16) = 512 blocks, 256 thr = 4 waves.
// Wave w: all 64 rows x 16 cols [n0+w*16, +16): 4 MFMA tiles 16x16x32, acc 16 f32.
// A tile (x^2,x) built on the fly from x into LDS each KB step.
__global__ __launch_bounds__(256, 2) void k_main(const float* __restrict__ x,
                                                 const ushort* __restrict__ Bb,
                                                 const float* __restrict__ c,
                                                 const float* __restrict__ temp,
                                                 float* __restrict__ out,
                                                 float* __restrict__ rowPartial) {
    const int t = threadIdx.x;
    const int w = t >> 6;
    const int lane = t & 63;
    const int m16 = lane & 15;
    const int q = lane >> 4;           // quad 0..3
    const int r0 = blockIdx.x * BM;
    const int n0 = blockIdx.y * BN;

    __shared__ ushort Alds[BM * LDA];  // 10240 B
    __shared__ float sums[4][BM];      // 1 KB

    f32x4 acc[4];
    #pragma unroll
    for (int rt = 0; rt < 4; ++rt) acc[rt] = (f32x4){0.f, 0.f, 0.f, 0.f};

    const float4* __restrict__ x4 = (const float4*)x;
    const int srow = t >> 3;           // 0..31 (staging row, first half)
    const int dq = t & 7;              // dim-quad: 4 dims -> 8 k elems

    const int fcol = n0 + w * 16 + m16;          // this lane's formula (B row)
    const ushort* __restrict__ Brow = Bb + fcol * K;

    for (int kb = 0; kb < K; kb += KB) {
        const int db4 = (kb >> 3);               // float4 index base into dim
        __syncthreads();
        // stage A: rows srow and srow+32, dims [kb/2 + dq*4, +4) -> 8 bf16
        #pragma unroll
        for (int h = 0; h < 2; ++h) {
            const int row = srow + h * 32;
            const float4 v = x4[(r0 + row) * (DIM / 4) + db4 + dq];
            short8 pk;
            pk[0] = (short)f2bf(v.x * v.x); pk[1] = (short)f2bf(v.x);
            pk[2] = (short)f2bf(v.y * v.y); pk[3] = (short)f2bf(v.y);
            pk[4] = (short)f2bf(v.z * v.z); pk[5] = (short)f2bf(v.z);
            pk[6] = (short)f2bf(v.w * v.w); pk[7] = (short)f2bf(v.w);
            *(short8*)&Alds[row * LDA + dq * 8] = pk;
        }
        __syncthreads();

        #pragma unroll
        for (int ks = 0; ks < KB; ks += 32) {
            const short8 bf = *(const short8*)&Brow[kb + ks + q * 8];
            #pragma unroll
            for (int rt = 0; rt < 4; ++rt) {
                const short8 af =
                    *(const short8*)&Alds[(rt * 16 + m16) * LDA + ks + q * 8];
                acc[rt] = __builtin_amdgcn_mfma_f32_16x16x32_bf16(af, bf, acc[rt], 0, 0, 0);
            }
        }
    }

    // epilogue: dist2 -> p = exp(g*exp(-dist)); store + row partial sums
    const float g = 1.0f / (1.0f + __expf(-temp[0]));
    const float cn = c[fcol];
    #pragma unroll
    for (int rt = 0; rt < 4; ++rt) {
        float s[4];
        #pragma unroll
        for (int i = 0; i < 4; ++i) {
            const float dist2 = acc[rt][i] + cn;
            const float dist = sqrtf(fmaxf(dist2, 0.0f));
            const float p = __expf(g * __expf(-dist));
            const int row = r0 + rt * 16 + q * 4 + i;
            out[row * NF + fcol] = p;
            s[i] = p;
        }
        // reduce over the 16 cols (lanes differing in low 4 bits)
        #pragma unroll
        for (int i = 0; i < 4; ++i) {
            #pragma unroll
            for (int mask = 1; mask < 16; mask <<= 1)
                s[i] += __shfl_xor(s[i], mask, 64);
        }
        if (m16 == 0) {
            #pragma unroll
            for (int i = 0; i < 4; ++i) sums[w][rt * 16 + q * 4 + i] = s[i];
        }
    }
    __syncthreads();
    if (t < BM) {
        rowPartial[blockIdx.y * BATCH + r0 + t] =
            sums[0][t] + sums[1][t] + sums[2][t] + sums[3][t];
    }
}

// ---------------------------------------------------------------------------
// K3: block = one batch row; normalize 1024 cols by the chunk-sum.
__global__ __launch_bounds__(256) void k_norm(float* __restrict__ out,
                                              const float* __restrict__ rowPartial) {
    const int row = blockIdx.x;                  // wave-uniform -> scalar loads
    float ssum = 0.0f;
    #pragma unroll
    for (int ch = 0; ch < NCHUNK; ++ch) ssum += rowPartial[ch * BATCH + row];
    const float inv = 1.0f / ssum;
    float4* o4 = (float4*)(out + row * NF);
    float4 v = o4[threadIdx.x];
    v.x *= inv; v.y *= inv; v.z *= inv; v.w *= inv;
    o4[threadIdx.x] = v;
}

extern "C" void kernel_launch(void* const* d_in, const int* in_sizes, int n_in,
                              void* d_out, int out_size, void* d_ws, size_t ws_size,
                              hipStream_t stream) {
    const float* x     = (const float*)d_in[0];
    const float* mu    = (const float*)d_in[1];
    const float* sigma = (const float*)d_in[2];
    const float* temp  = (const float*)d_in[3];
    float* out = (float*)d_out;

    char* ws = (char*)d_ws;
    ushort* Bb        = (ushort*)ws;
    float*  c         = (float*)(ws + WS_C_OFF);
    float*  rowPartial = (float*)(ws + WS_RP_OFF);

    k_prep<<<NF + 32, 256, 0, stream>>>(mu, sigma, (unsigned int*)Bb, c,
                                        (float4*)rowPartial);

    dim3 g2(BATCH / BM, NF / BN);
    k_main<<<g2, 256, 0, stream>>>(x, Bb, c, temp, out, rowPartial);

    k_norm<<<BATCH, 256, 0, stream>>>(out, rowPartial);
}

// Round 3
// 80.752 us; speedup vs baseline: 1.8179x; 1.0326x over previous
//
#include <hip/hip_runtime.h>
#include <math.h>

#define NF 1024
#define DIM 256
#define BATCH 2048
#define K 512            // interleaved (x^2, x) -> 2*DIM
#define BM 64
#define BN 64
#define KB 64            // K elems per staged chunk (8 chunks of 8)
#define NCHUNK (NF / BN) // 16

// ws layout (16B aligned):
//   [0, 2MB)    : Ab bf16[BATCH][K]  rows: (x^2, x) interleaved per dim
//   [2MB, 3MB)  : Bb bf16[NF][K]     rows: (s2, -2*s2*mu) interleaved per dim
//   [3MB, +4KB) : c  float[NF]
//   then        : rowPartial float[NCHUNK][BATCH]  (fully overwritten, no zeroing)
#define WS_A_BYTES (BATCH * K * 2)
#define WS_B_OFF   WS_A_BYTES
#define WS_C_OFF   (WS_A_BYTES + NF * K * 2)
#define WS_RP_OFF  (WS_C_OFF + NF * 4)

typedef __attribute__((ext_vector_type(8))) short short8;   // 8 bf16
typedef __attribute__((ext_vector_type(4))) float f32x4;    // MFMA acc

__device__ __forceinline__ unsigned short f2bf(float f) {
    unsigned u = __float_as_uint(f);
    u += 0x7fffu + ((u >> 16) & 1u);       // RNE
    return (unsigned short)(u >> 16);
}

// async global->LDS, 16B per lane; LDS dest must be uniform-base + lane*16
__device__ __forceinline__ void gl_lds16(const ushort* g, ushort* l) {
    __builtin_amdgcn_global_load_lds(
        (const __attribute__((address_space(1))) void*)g,
        (__attribute__((address_space(3))) void*)l, 16, 0, 0);
}

// ---------------------------------------------------------------------------
// K1: blocks [0,NF): formula f -> Bb row (coalesced u32 stores) + c[f].
//     blocks [NF, NF+BATCH*DIM/256): pack x -> Ab (coalesced u32 stores).
__global__ __launch_bounds__(256) void k_prep(const float* __restrict__ mu,
                                              const float* __restrict__ sigma,
                                              const float* __restrict__ x,
                                              unsigned int* __restrict__ Ab32,
                                              unsigned int* __restrict__ Bb32,
                                              float* __restrict__ c) {
    const int t = threadIdx.x;
    if (blockIdx.x >= NF) {
        const int i = (blockIdx.x - NF) * 256 + t;       // row*DIM + d
        const float v = x[i];
        Ab32[i] = (unsigned)f2bf(v * v) | ((unsigned)f2bf(v) << 16);
        return;
    }
    const int f = blockIdx.x;
    const float m = mu[f * DIM + t];
    const float s = sigma[f * DIM + t];
    const float s2 = s * s;
    Bb32[f * DIM + t] = (unsigned)f2bf(s2) | ((unsigned)f2bf(-2.0f * s2 * m) << 16);

    float cp = s2 * m * m;
    #pragma unroll
    for (int off = 32; off > 0; off >>= 1) cp += __shfl_down(cp, off, 64);
    __shared__ float red[4];
    const int lane = t & 63, wv = t >> 6;
    if (lane == 0) red[wv] = cp;
    __syncthreads();
    if (t == 0) c[f] = red[0] + red[1] + red[2] + red[3];
}

// ---------------------------------------------------------------------------
// K2: bf16 MFMA GEMM + exp epilogue. Grid (32,16)=512 blocks, 4 waves.
// Waves 2x2: wave w=(wr,wc) computes rows [wr*32,+32) x cols [wc*32,+32)
// as 2x2 MFMA 16x16x32 tiles. A/B chunks staged async via global_load_lds
// into XOR-swizzled slots: slot(row,kc) = row*8 + (kc ^ (row&7)); the
// swizzle makes ds_read_b128 2-way on banks (free) with zero padding.
__global__ __launch_bounds__(256, 2) void k_main(const ushort* __restrict__ Ab,
                                                 const ushort* __restrict__ Bb,
                                                 const float* __restrict__ c,
                                                 const float* __restrict__ temp,
                                                 float* __restrict__ out,
                                                 float* __restrict__ rowPartial) {
    const int t = threadIdx.x;
    const int w = t >> 6;
    const int lane = t & 63;
    const int m16 = lane & 15;
    const int q = lane >> 4;
    const int wr = w >> 1, wc = w & 1;
    const int r0 = blockIdx.x * BM;
    const int n0 = blockIdx.y * BN;

    __shared__ __align__(16) ushort lds[8192];   // A: slots 0..511, B: 512..1023
    __shared__ float sums[4][32];

    f32x4 acc[2][2];
    #pragma unroll
    for (int rt = 0; rt < 2; ++rt)
        #pragma unroll
        for (int ct = 0; ct < 2; ++ct) acc[rt][ct] = (f32x4){0.f, 0.f, 0.f, 0.f};

    // staging geometry (2 insts each for A and B, 256 lanes x 16B)
    int srow[2], skc[2];
    #pragma unroll
    for (int h = 0; h < 2; ++h) {
        const int s = h * 256 + t;
        srow[h] = s >> 3;
        skc[h] = (s & 7) ^ (srow[h] & 7);
    }

    for (int kb = 0; kb < K; kb += KB) {
        __syncthreads();                          // protect prev iter's reads
        #pragma unroll
        for (int h = 0; h < 2; ++h) {
            const int s = h * 256 + t;
            gl_lds16(Ab + (r0 + srow[h]) * K + kb + skc[h] * 8, &lds[s * 8]);
            gl_lds16(Bb + (n0 + srow[h]) * K + kb + skc[h] * 8, &lds[4096 + s * 8]);
        }
        __syncthreads();                          // vmcnt(0) drain + barrier

        #pragma unroll
        for (int ks = 0; ks < KB; ks += 32) {
            const int kcq = (ks >> 3) + q;
            short8 av[2], bv[2];
            #pragma unroll
            for (int j = 0; j < 2; ++j) {
                const int ar = wr * 32 + j * 16 + m16;
                av[j] = *(const short8*)&lds[(ar * 8 + (kcq ^ (ar & 7))) * 8];
                const int fr = wc * 32 + j * 16 + m16;
                bv[j] = *(const short8*)&lds[4096 + (fr * 8 + (kcq ^ (fr & 7))) * 8];
            }
            #pragma unroll
            for (int rt = 0; rt < 2; ++rt)
                #pragma unroll
                for (int ct = 0; ct < 2; ++ct)
                    acc[rt][ct] = __builtin_amdgcn_mfma_f32_16x16x32_bf16(
                        av[rt], bv[ct], acc[rt][ct], 0, 0, 0);
        }
    }

    // epilogue: dist2 -> p = exp(g*exp(-dist)); store + deterministic partials
    const float g = 1.0f / (1.0f + __expf(-temp[0]));
    #pragma unroll
    for (int rt = 0; rt < 2; ++rt) {
        float s[4] = {0.f, 0.f, 0.f, 0.f};
        #pragma unroll
        for (int ct = 0; ct < 2; ++ct) {
            const int fcol = n0 + wc * 32 + ct * 16 + m16;
            const float cn = c[fcol];
            #pragma unroll
            for (int i = 0; i < 4; ++i) {
                const float dist2 = acc[rt][ct][i] + cn;
                const float dist = sqrtf(fmaxf(dist2, 0.0f));
                const float p = __expf(g * __expf(-dist));
                const int row = r0 + wr * 32 + rt * 16 + q * 4 + i;
                out[row * NF + fcol] = p;
                s[i] += p;
            }
        }
        #pragma unroll
        for (int i = 0; i < 4; ++i) {
            #pragma unroll
            for (int mask = 1; mask < 16; mask <<= 1)
                s[i] += __shfl_xor(s[i], mask, 64);
        }
        if (m16 == 0) {
            #pragma unroll
            for (int i = 0; i < 4; ++i) sums[w][rt * 16 + q * 4 + i] = s[i];
        }
    }
    __syncthreads();
    if (t < BM) {
        const int half = t >> 5, lr = t & 31;
        rowPartial[blockIdx.y * BATCH + r0 + t] =
            sums[half * 2][lr] + sums[half * 2 + 1][lr];
    }
}

// ---------------------------------------------------------------------------
// K3: block = one batch row; normalize by the 16 chunk-sums (scalar loads).
__global__ __launch_bounds__(256) void k_norm(float* __restrict__ out,
                                              const float* __restrict__ rowPartial) {
    const int row = blockIdx.x;
    float ssum = 0.0f;
    #pragma unroll
    for (int ch = 0; ch < NCHUNK; ++ch) ssum += rowPartial[ch * BATCH + row];
    const float inv = 1.0f / ssum;
    float4* o4 = (float4*)(out + row * NF);
    float4 v = o4[threadIdx.x];
    v.x *= inv; v.y *= inv; v.z *= inv; v.w *= inv;
    o4[threadIdx.x] = v;
}

extern "C" void kernel_launch(void* const* d_in, const int* in_sizes, int n_in,
                              void* d_out, int out_size, void* d_ws, size_t ws_size,
                              hipStream_t stream) {
    const float* x     = (const float*)d_in[0];
    const float* mu    = (const float*)d_in[1];
    const float* sigma = (const float*)d_in[2];
    const float* temp  = (const float*)d_in[3];
    float* out = (float*)d_out;

    char* ws = (char*)d_ws;
    ushort* Ab        = (ushort*)ws;
    ushort* Bb        = (ushort*)(ws + WS_B_OFF);
    float*  c         = (float*)(ws + WS_C_OFF);
    float*  rowPartial = (float*)(ws + WS_RP_OFF);

    k_prep<<<NF + BATCH * DIM / 256, 256, 0, stream>>>(mu, sigma, x,
                                                       (unsigned int*)Ab,
                                                       (unsigned int*)Bb, c);

    dim3 g2(BATCH / BM, NF / BN);
    k_main<<<g2, 256, 0, stream>>>(Ab, Bb, c, temp, out, rowPartial);

    k_norm<<<BATCH, 256, 0, stream>>>(out, rowPartial);
}